// Round 6
// baseline (2556.880 us; speedup 1.0000x reference)
//
#include <hip/hip_runtime.h>
#include <cstdint>
#include <cstddef>

#define B_Q 1024
#define N_MEM 100000
#define DIM 256
#define TOPK 16
#define CQ 128                 // queries per chunk
#define NCHUNK (B_Q / CQ)      // 8
#define BRG 128                // memory rows per gemm block tile
#define RSTRIDE 100000         // sims row stride (floats) per query
#define SPLITS 32
#define SPLIT_ROWS 3125        // N_MEM / SPLITS
#define EPSF 1e-8f
#define INV_T (1.0f / 0.07f)
#define NEG_INF (-1e30f)

#define MIN16(t) fminf(fminf(fminf(fminf(t[0],t[1]),fminf(t[2],t[3])),fminf(fminf(t[4],t[5]),fminf(t[6],t[7]))), \
                       fminf(fminf(fminf(t[8],t[9]),fminf(t[10],t[11])),fminf(fminf(t[12],t[13]),fminf(t[14],t[15]))))
#define MAX16(t) fmaxf(fmaxf(fmaxf(fmaxf(t[0],t[1]),fmaxf(t[2],t[3])),fmaxf(fmaxf(t[4],t[5]),fmaxf(t[6],t[7]))), \
                       fmaxf(fmaxf(fmaxf(t[8],t[9]),fmaxf(t[10],t[11])),fmaxf(fmaxf(t[12],t[13]),fmaxf(t[14],t[15]))))
#define MAX8(t) fmaxf(fmaxf(fmaxf(t[0],t[1]),fmaxf(t[2],t[3])),fmaxf(fmaxf(t[4],t[5]),fmaxf(t[6],t[7])))

// ---------------- norms: inv L2 norm of every memory row and query row ----------------
__global__ __launch_bounds__(256) void k_norms(const float* __restrict__ q,
                                               const float* __restrict__ m,
                                               float* __restrict__ invq,
                                               float* __restrict__ invm) {
    int wid  = blockIdx.x * 4 + (threadIdx.x >> 6);   // one wave per row
    int lane = threadIdx.x & 63;
    if (wid >= N_MEM + B_Q) return;
    const float* src = (wid < N_MEM) ? (m + (size_t)wid * DIM)
                                     : (q + (size_t)(wid - N_MEM) * DIM);
    float4 v = ((const float4*)src)[lane];            // 64 lanes x 4 = 256 floats
    float ss = v.x*v.x + v.y*v.y + v.z*v.z + v.w*v.w;
#pragma unroll
    for (int off = 32; off > 0; off >>= 1) ss += __shfl_xor(ss, off);
    if (lane == 0) {
        float inv = 1.0f / fmaxf(sqrtf(ss), EPSF);
        if (wid < N_MEM) invm[wid] = inv;
        else             invq[wid - N_MEM] = inv;
    }
}

// ---------------- fp32 GEMM: sims[q][r] = dot(query[q], mem[r]) * invq * invm ----------------
// block tile: 128q (whole chunk) x 128r; thread tile 8q x 8r; K tiled by 32.
// LDS [row][33] (pad +1 float -> 2-way staging-store aliasing = free).
// Thread's 8 r rows: {rg*4+0..3} and {64+rg*4+0..3} so epilogue stores are 256B-contiguous per instr.
__global__ __launch_bounds__(256) void k_gemm(const float* __restrict__ query,
                                              const float* __restrict__ mem,
                                              const float* __restrict__ invq,
                                              const float* __restrict__ invm,
                                              float* __restrict__ sims,
                                              int chunk) {
    __shared__ float qT[128][33];
    __shared__ float mT[128][33];
    const int tid = threadIdx.x;
    const int rowbase = blockIdx.x * BRG;
    const int qg = tid >> 4;          // 0..15 -> q0 = qg*8
    const int rg = tid & 15;          // 0..15 -> rows rg*4 + {0..3}, 64 + rg*4 + {0..3}
    const int q0 = qg * 8;

    float acc[8][8];
#pragma unroll
    for (int i = 0; i < 8; ++i)
#pragma unroll
        for (int j = 0; j < 8; ++j) acc[i][j] = 0.f;

    const float* qbase = query + (size_t)(chunk * CQ) * DIM;

    for (int dt = 0; dt < DIM / 32; ++dt) {           // 8 K-tiles of 32
        const int d0 = dt * 32;
        __syncthreads();                               // previous compute done with LDS
        // stage 128x32 of q and mem: f = k*256+tid -> row=f>>3, dseg=f&7 (1KB contiguous per wave instr)
#pragma unroll
        for (int k = 0; k < 4; ++k) {
            int f = k * 256 + tid;
            int row = f >> 3, ds = (f & 7) * 4;
            float4 v = *(const float4*)(qbase + (size_t)row * DIM + d0 + ds);
            *(float4*)&qT[row][ds] = v;
            int grow = rowbase + row;
            float4 w = make_float4(0.f, 0.f, 0.f, 0.f);
            if (grow < N_MEM) w = *(const float4*)(mem + (size_t)grow * DIM + d0 + ds);
            *(float4*)&mT[row][ds] = w;
        }
        __syncthreads();
#pragma unroll
        for (int dd = 0; dd < 8; ++dd) {              // 4 d's per step
            float4 qf[8];
#pragma unroll
            for (int i = 0; i < 8; ++i) qf[i] = *(const float4*)&qT[q0 + i][dd * 4];
#pragma unroll
            for (int j = 0; j < 8; ++j) {
                const int rl = (j < 4) ? (rg * 4 + j) : (64 + rg * 4 + j - 4);
                float4 mf = *(const float4*)&mT[rl][dd * 4];
#pragma unroll
                for (int i = 0; i < 8; ++i) {
                    acc[i][j] = fmaf(qf[i].x, mf.x, acc[i][j]);
                    acc[i][j] = fmaf(qf[i].y, mf.y, acc[i][j]);
                    acc[i][j] = fmaf(qf[i].z, mf.z, acc[i][j]);
                    acc[i][j] = fmaf(qf[i].w, mf.w, acc[i][j]);
                }
            }
        }
    }

    // epilogue: scale by inverse norms, store query-major sims[q][r]
    float iq[8];
#pragma unroll
    for (int i = 0; i < 8; ++i) iq[i] = invq[chunk * CQ + q0 + i];

    if (rowbase + BRG <= N_MEM) {                     // fast path: full tile in range
        float im[8];
#pragma unroll
        for (int j = 0; j < 8; ++j) {
            const int rl = (j < 4) ? (rg * 4 + j) : (64 + rg * 4 + j - 4);
            im[j] = invm[rowbase + rl];
        }
#pragma unroll
        for (int i = 0; i < 8; ++i) {
            float s = iq[i];
            float4 a = make_float4(acc[i][0]*s*im[0], acc[i][1]*s*im[1],
                                   acc[i][2]*s*im[2], acc[i][3]*s*im[3]);
            float4 b = make_float4(acc[i][4]*s*im[4], acc[i][5]*s*im[5],
                                   acc[i][6]*s*im[6], acc[i][7]*s*im[7]);
            size_t base = (size_t)(q0 + i) * RSTRIDE + rowbase;
            *(float4*)(sims + base + rg * 4)      = a;
            *(float4*)(sims + base + 64 + rg * 4) = b;
        }
    } else {                                          // boundary block: scalar guarded
#pragma unroll
        for (int i = 0; i < 8; ++i) {
            float s = iq[i];
#pragma unroll
            for (int j = 0; j < 8; ++j) {
                const int rl = (j < 4) ? (rg * 4 + j) : (64 + rg * 4 + j - 4);
                int r = rowbase + rl;
                if (r < N_MEM)
                    sims[(size_t)(q0 + i) * RSTRIDE + r] = acc[i][j] * s * invm[r];
            }
        }
    }
}

// ---------------- per-(query, split) exact top-16: one wave per (q, 3125-row split) ----------------
// coalesced query-major scan (256B per wave instr), per-lane 16-deep min-replace,
// then 16-round wave extraction (same verified pattern as before).
__global__ __launch_bounds__(64) void k_topk_part(const float* __restrict__ sims,
                                                  float* __restrict__ part_v,
                                                  int* __restrict__ part_i) {
    const int qc   = blockIdx.x;       // 0..127 chunk-local query
    const int s    = blockIdx.y;       // 0..31
    const int lane = threadIdx.x;      // 0..63
    const float* row = sims + (size_t)qc * RSTRIDE;
    const int rstart = s * SPLIT_ROWS;
    const int rend   = rstart + SPLIT_ROWS;   // N_MEM divisible by SPLITS

    float tv[16]; int ti[16];
#pragma unroll
    for (int j = 0; j < 16; ++j) { tv[j] = NEG_INF; ti[j] = 0; }
    float cmin = NEG_INF;

    for (int r = rstart + lane; r < rend; r += 64) {
        float v = row[r];
        if (v > cmin) {
            bool done = false;
#pragma unroll
            for (int j = 0; j < 16; ++j) {
                bool hit = (!done) && (tv[j] == cmin);
                if (hit) { tv[j] = v; ti[j] = r; done = true; }
            }
            cmin = MIN16(tv);
        }
    }

    // wave extraction of top-16 from 64 lanes x 16
    for (int round = 0; round < 16; ++round) {
        float mymax = MAX16(tv);
        float g = mymax;
#pragma unroll
        for (int off = 32; off > 0; off >>= 1) g = fmaxf(g, __shfl_xor(g, off));
        unsigned long long bal = __ballot(mymax == g);
        int winner = __ffsll(bal) - 1;
        if (lane == winner) {
            bool done = false;
#pragma unroll
            for (int j = 0; j < 16; ++j) {
                bool hit = (!done) && (tv[j] == g);
                if (hit) {
                    part_v[qc * (SPLITS * 16) + s * 16 + round] = g;
                    part_i[qc * (SPLITS * 16) + s * 16 + round] = ti[j];
                    tv[j] = NEG_INF; done = true;
                }
            }
        }
    }
}

// ---------------- merge 32 splits x 16 -> final top-16 per query (one wave per query) ----------------
__global__ __launch_bounds__(256) void k_topk_merge(const float* __restrict__ part_v,
                                                    const int* __restrict__ part_i,
                                                    float* __restrict__ topv,
                                                    int* __restrict__ topi,
                                                    int chunk) {
    const int tid  = threadIdx.x;
    const int lane = tid & 63;
    const int qc   = blockIdx.x * 4 + (tid >> 6);
    float cv[8]; int ci[8];
#pragma unroll
    for (int t = 0; t < 8; ++t) {
        cv[t] = part_v[qc * 512 + t * 64 + lane];
        ci[t] = part_i[qc * 512 + t * 64 + lane];
    }
    const int qglob = chunk * CQ + qc;
    for (int round = 0; round < 16; ++round) {
        float mymax = MAX8(cv);
        float g = mymax;
#pragma unroll
        for (int off = 32; off > 0; off >>= 1) g = fmaxf(g, __shfl_xor(g, off));
        unsigned long long bal = __ballot(mymax == g);
        int winner = __ffsll(bal) - 1;
        if (lane == winner) {
            bool done = false;
#pragma unroll
            for (int j = 0; j < 8; ++j) {
                bool hit = (!done) && (cv[j] == g);
                if (hit) {
                    topv[qglob * 16 + round] = g;
                    topi[qglob * 16 + round] = ci[j];
                    cv[j] = NEG_INF; done = true;
                }
            }
        }
    }
}

// ---------------- softmax gather + subjective-logic fusion (K=2) ----------------
__global__ __launch_bounds__(256) void k_fuse(const float* __restrict__ topv,
                                              const int* __restrict__ topi,
                                              const float* __restrict__ mem_ev,
                                              const float* __restrict__ model_ev,
                                              float* __restrict__ out) {
    int q = blockIdx.x * blockDim.x + threadIdx.x;
    if (q >= B_Q) return;
    float tv[16]; int ti[16];
#pragma unroll
    for (int j = 0; j < 16; ++j) { tv[j] = topv[q * 16 + j]; ti[j] = topi[q * 16 + j]; }
    float mx = tv[0];
#pragma unroll
    for (int j = 1; j < 16; ++j) mx = fmaxf(mx, tv[j]);
    float es[16], ssum = 0.f;
#pragma unroll
    for (int j = 0; j < 16; ++j) { es[j] = expf((tv[j] - mx) * INV_T); ssum += es[j]; }
    float inv_s = 1.0f / ssum;
    float ar0 = 0.f, ar1 = 0.f;
#pragma unroll
    for (int j = 0; j < 16; ++j) {
        float w = es[j] * inv_s;
        const float* e = mem_ev + (size_t)ti[j] * 2;
        ar0 = fmaf(w, e[0], ar0);
        ar1 = fmaf(w, e[1], ar1);
    }
    float am0 = model_ev[q * 2 + 0] + 1.0f;
    float am1 = model_ev[q * 2 + 1] + 1.0f;
    float arr0 = ar0 + 1.0f, arr1 = ar1 + 1.0f;

    auto belief = [](float a0, float a1, float& b0, float& b1, float& u) {
        float S = fmaxf(a0 + a1, EPSF);
        b0 = fmaxf((a0 - 1.f) / S, 0.f);
        b1 = fmaxf((a1 - 1.f) / S, 0.f);
        u  = fminf(fmaxf(2.f / S, EPSF), 1.f - EPSF);
        float bs = b0 + b1;
        float target = fmaxf(1.f - u, EPSF);
        float sc = target / fmaxf(bs, EPSF);
        b0 *= sc; b1 *= sc;
    };
    float bm0, bm1, um, br0, br1, ur;
    belief(am0, am1, bm0, bm1, um);
    belief(arr0, arr1, br0, br1, ur);

    float total_pair = (bm0 + bm1) * (br0 + br1);
    float dot_same   = bm0 * br0 + bm1 * br1;
    float C = total_pair - dot_same;
    float S = fmaxf(1.f - C, EPSF);
    float b0 = (bm0 * br0 + bm0 * ur + br0 * um) / S;
    float b1 = (bm1 * br1 + bm1 * ur + br1 * um) / S;
    float u  = um * ur / S;
    b0 = fmaxf(b0, 0.f); b1 = fmaxf(b1, 0.f);
    u = fminf(fmaxf(u, EPSF), 1.f - EPSF);
    float bs = b0 + b1;
    float sc = (1.f - u) / fmaxf(bs, EPSF);
    b0 *= sc; b1 *= sc;
    float Sf = 2.f / u;
    float a0 = b0 * Sf + 1.f, a1 = b1 * Sf + 1.f;
    out[q * 2 + 0] = fmaxf(a0, 1.f + EPSF);
    out[q * 2 + 1] = fmaxf(a1, 1.f + EPSF);
}

// ---------------- launch ----------------
extern "C" void kernel_launch(void* const* d_in, const int* in_sizes, int n_in,
                              void* d_out, int out_size, void* d_ws, size_t ws_size,
                              hipStream_t stream) {
    const float* query    = (const float*)d_in[0];
    const float* mem      = (const float*)d_in[1];
    const float* mem_ev   = (const float*)d_in[2];
    const float* model_ev = (const float*)d_in[3];
    char* ws = (char*)d_ws;
    // ws layout (bytes): invq 4K | invm 400K | part_v 512K | part_i 512K | topv 64K | topi 64K | sims 51.2M
    float* invq   = (float*)(ws + 0);
    float* invm   = (float*)(ws + 4096);
    float* part_v = (float*)(ws + 404480);
    int*   part_i = (int*)  (ws + 404480 + 524288);
    float* topv   = (float*)(ws + 1453056);
    int*   topi   = (int*)  (ws + 1518592);
    float* sims   = (float*)(ws + 1585152);           // 128 * 100000 * 4B = 51.2 MB

    k_norms<<<(N_MEM + B_Q + 3) / 4, 256, 0, stream>>>(query, mem, invq, invm);
    for (int c = 0; c < NCHUNK; ++c) {
        k_gemm<<<(N_MEM + BRG - 1) / BRG, 256, 0, stream>>>(query, mem, invq, invm, sims, c);
        k_topk_part<<<dim3(CQ, SPLITS), 64, 0, stream>>>(sims, part_v, part_i);
        k_topk_merge<<<32, 256, 0, stream>>>(part_v, part_i, topv, topi, c);
    }
    k_fuse<<<4, 256, 0, stream>>>(topv, topi, mem_ev, model_ev, (float*)d_out);
}

// Round 7
// 1796.054 us; speedup vs baseline: 1.4236x; 1.4236x over previous
//
#include <hip/hip_runtime.h>
#include <cstdint>
#include <cstddef>

#define B_Q 1024
#define N_MEM 100000
#define DIM 256
#define TOPK 16
#define CQ 128                 // queries per chunk
#define NCHUNK (B_Q / CQ)      // 8
#define BR 64                  // memory rows per gemm block tile
#define BD 32                  // d per LDS tile
#define RSTRIDE 100000         // sims row stride (floats) per query
#define SPLITS 32
#define SPLIT_ROWS 3125        // N_MEM / SPLITS
#define EPSF 1e-8f
#define INV_T (1.0f / 0.07f)
#define NEG_INF (-1e30f)

#define MIN16(t) fminf(fminf(fminf(fminf(t[0],t[1]),fminf(t[2],t[3])),fminf(fminf(t[4],t[5]),fminf(t[6],t[7]))), \
                       fminf(fminf(fminf(t[8],t[9]),fminf(t[10],t[11])),fminf(fminf(t[12],t[13]),fminf(t[14],t[15]))))
#define MAX16(t) fmaxf(fmaxf(fmaxf(fmaxf(t[0],t[1]),fmaxf(t[2],t[3])),fmaxf(fmaxf(t[4],t[5]),fmaxf(t[6],t[7]))), \
                       fmaxf(fmaxf(fmaxf(t[8],t[9]),fmaxf(t[10],t[11])),fmaxf(fmaxf(t[12],t[13]),fmaxf(t[14],t[15]))))
#define MAX8(t) fmaxf(fmaxf(fmaxf(t[0],t[1]),fmaxf(t[2],t[3])),fmaxf(fmaxf(t[4],t[5]),fmaxf(t[6],t[7])))

// ---------------- norms: inv L2 norm of every memory row and query row ----------------
__global__ __launch_bounds__(256) void k_norms(const float* __restrict__ q,
                                               const float* __restrict__ m,
                                               float* __restrict__ invq,
                                               float* __restrict__ invm) {
    int wid  = blockIdx.x * 4 + (threadIdx.x >> 6);   // one wave per row
    int lane = threadIdx.x & 63;
    if (wid >= N_MEM + B_Q) return;
    const float* src = (wid < N_MEM) ? (m + (size_t)wid * DIM)
                                     : (q + (size_t)(wid - N_MEM) * DIM);
    float4 v = ((const float4*)src)[lane];            // 64 lanes x 4 = 256 floats
    float ss = v.x*v.x + v.y*v.y + v.z*v.z + v.w*v.w;
#pragma unroll
    for (int off = 32; off > 0; off >>= 1) ss += __shfl_xor(ss, off);
    if (lane == 0) {
        float inv = 1.0f / fmaxf(sqrtf(ss), EPSF);
        if (wid < N_MEM) invm[wid] = inv;
        else             invq[wid - N_MEM] = inv;
    }
}

// ---------------- fp32 GEMM (proven R4 inner structure): 128q x 64r block, 4q x 8r thread ----------------
// K tiled by 32, LDS transposed [d][q] / [d][r]. NEW: q-major epilogue via LDS transpose
// (reuses dead mT buffer, 4 passes of 32 q) so sims[q][r] scans are coalesced for topk.
__global__ __launch_bounds__(256, 4) void k_gemm(const float* __restrict__ query,
                                                 const float* __restrict__ mem,
                                                 const float* __restrict__ invq,
                                                 const float* __restrict__ invm,
                                                 float* __restrict__ sims,
                                                 int chunk) {
    __shared__ float qT[BD][132];   // [d][q]  pad 132
    __shared__ float mT[BD][68];    // [d][r]  pad 68; reused as [32][68] transpose buffer
    const int tid = threadIdx.x;
    const int rowbase = blockIdx.x * BR;
    const int qg = tid & 31, rg = tid >> 5;
    const int q0 = qg * 4,  r0 = rg * 8;
    const int seg  = tid & 7;    // d-segment (x4 floats)
    const int lrow = tid >> 3;   // 0..31

    float acc[4][8];
#pragma unroll
    for (int i = 0; i < 4; ++i)
#pragma unroll
        for (int j = 0; j < 8; ++j) acc[i][j] = 0.f;

    const float* qbase = query + (size_t)(chunk * CQ) * DIM;

    for (int dt = 0; dt < DIM / BD; ++dt) {
        const int d0 = dt * BD;
        // stage queries: 128 rows x 32 d, transposed into LDS
#pragma unroll
        for (int p = 0; p < 4; ++p) {
            int qr = p * 32 + lrow;
            float4 v = *(const float4*)(qbase + (size_t)qr * DIM + d0 + seg * 4);
            qT[seg*4+0][qr] = v.x; qT[seg*4+1][qr] = v.y;
            qT[seg*4+2][qr] = v.z; qT[seg*4+3][qr] = v.w;
        }
        // stage memory rows: 64 x 32, transposed
#pragma unroll
        for (int p = 0; p < 2; ++p) {
            int mr = p * 32 + lrow;
            int grow = rowbase + mr;
            float4 v = make_float4(0.f, 0.f, 0.f, 0.f);
            if (grow < N_MEM) v = *(const float4*)(mem + (size_t)grow * DIM + d0 + seg * 4);
            mT[seg*4+0][mr] = v.x; mT[seg*4+1][mr] = v.y;
            mT[seg*4+2][mr] = v.z; mT[seg*4+3][mr] = v.w;
        }
        __syncthreads();
#pragma unroll
        for (int d = 0; d < BD; ++d) {
            float4 qv = *(const float4*)&qT[d][q0];
            float4 m0 = *(const float4*)&mT[d][r0];
            float4 m1 = *(const float4*)&mT[d][r0 + 4];
            float qa[4] = {qv.x, qv.y, qv.z, qv.w};
            float mb[8] = {m0.x, m0.y, m0.z, m0.w, m1.x, m1.y, m1.z, m1.w};
#pragma unroll
            for (int i = 0; i < 4; ++i)
#pragma unroll
                for (int j = 0; j < 8; ++j)
                    acc[i][j] = fmaf(qa[i], mb[j], acc[i][j]);
        }
        __syncthreads();
    }

    // scale by inverse norms in registers
    float iq[4];
#pragma unroll
    for (int i = 0; i < 4; ++i) iq[i] = invq[chunk * CQ + q0 + i];
    float im[8];
#pragma unroll
    for (int j = 0; j < 8; ++j) {
        int r = rowbase + r0 + j;
        im[j] = (r < N_MEM) ? invm[r] : 0.f;
    }
#pragma unroll
    for (int i = 0; i < 4; ++i)
#pragma unroll
        for (int j = 0; j < 8; ++j) acc[i][j] *= iq[i] * im[j];

    // q-major epilogue: 4 passes of 32 q through the dead mT buffer ([32][68])
    float (*tb)[68] = (float (*)[68])mT;
    const int q32  = tid >> 4;          // 0..15 (reader role)
    const int rl4  = (tid & 15) * 4;
#pragma unroll
    for (int p = 0; p < 4; ++p) {
        __syncthreads();                // previous pass reads / K-loop done with mT
        if ((qg >> 3) == p) {           // this thread's 4 q's fall in [32p, 32p+32)
            int qb = (qg & 7) * 4;
#pragma unroll
            for (int i = 0; i < 4; ++i)
#pragma unroll
                for (int j = 0; j < 8; ++j)
                    tb[qb + i][r0 + j] = acc[i][j];
        }
        __syncthreads();
        // cooperative coalesced store: 32 q x 64 r, 256B contiguous per 16-lane group
#pragma unroll
        for (int h = 0; h < 2; ++h) {
            int qq = q32 + h * 16;                   // 0..31
            int qc = p * 32 + qq;                    // chunk-local query
            int r  = rowbase + rl4;
            if (r + 3 < N_MEM) {
                *(float4*)(sims + (size_t)qc * RSTRIDE + r) = *(float4*)&tb[qq][rl4];
            } else {
#pragma unroll
                for (int c = 0; c < 4; ++c)
                    if (r + c < N_MEM)
                        sims[(size_t)qc * RSTRIDE + r + c] = tb[qq][rl4 + c];
            }
        }
    }
}

// ---------------- per-(query, split) exact top-16: one wave per (q, 3125-row split) ----------------
__global__ __launch_bounds__(64) void k_topk_part(const float* __restrict__ sims,
                                                  float* __restrict__ part_v,
                                                  int* __restrict__ part_i) {
    const int qc   = blockIdx.x;       // 0..127 chunk-local query
    const int s    = blockIdx.y;       // 0..31
    const int lane = threadIdx.x;      // 0..63
    const float* row = sims + (size_t)qc * RSTRIDE;
    const int rstart = s * SPLIT_ROWS;
    const int rend   = rstart + SPLIT_ROWS;   // N_MEM divisible by SPLITS

    float tv[16]; int ti[16];
#pragma unroll
    for (int j = 0; j < 16; ++j) { tv[j] = NEG_INF; ti[j] = 0; }
    float cmin = NEG_INF;

    for (int r = rstart + lane; r < rend; r += 64) {
        float v = row[r];
        if (v > cmin) {
            bool done = false;
#pragma unroll
            for (int j = 0; j < 16; ++j) {
                bool hit = (!done) && (tv[j] == cmin);
                if (hit) { tv[j] = v; ti[j] = r; done = true; }
            }
            cmin = MIN16(tv);
        }
    }

    // wave extraction of top-16 from 64 lanes x 16
    for (int round = 0; round < 16; ++round) {
        float mymax = MAX16(tv);
        float g = mymax;
#pragma unroll
        for (int off = 32; off > 0; off >>= 1) g = fmaxf(g, __shfl_xor(g, off));
        unsigned long long bal = __ballot(mymax == g);
        int winner = __ffsll(bal) - 1;
        if (lane == winner) {
            bool done = false;
#pragma unroll
            for (int j = 0; j < 16; ++j) {
                bool hit = (!done) && (tv[j] == g);
                if (hit) {
                    part_v[qc * (SPLITS * 16) + s * 16 + round] = g;
                    part_i[qc * (SPLITS * 16) + s * 16 + round] = ti[j];
                    tv[j] = NEG_INF; done = true;
                }
            }
        }
    }
}

// ---------------- merge 32 splits x 16 -> final top-16 per query (one wave per query) ----------------
__global__ __launch_bounds__(256) void k_topk_merge(const float* __restrict__ part_v,
                                                    const int* __restrict__ part_i,
                                                    float* __restrict__ topv,
                                                    int* __restrict__ topi,
                                                    int chunk) {
    const int tid  = threadIdx.x;
    const int lane = tid & 63;
    const int qc   = blockIdx.x * 4 + (tid >> 6);
    float cv[8]; int ci[8];
#pragma unroll
    for (int t = 0; t < 8; ++t) {
        cv[t] = part_v[qc * 512 + t * 64 + lane];
        ci[t] = part_i[qc * 512 + t * 64 + lane];
    }
    const int qglob = chunk * CQ + qc;
    for (int round = 0; round < 16; ++round) {
        float mymax = MAX8(cv);
        float g = mymax;
#pragma unroll
        for (int off = 32; off > 0; off >>= 1) g = fmaxf(g, __shfl_xor(g, off));
        unsigned long long bal = __ballot(mymax == g);
        int winner = __ffsll(bal) - 1;
        if (lane == winner) {
            bool done = false;
#pragma unroll
            for (int j = 0; j < 8; ++j) {
                bool hit = (!done) && (cv[j] == g);
                if (hit) {
                    topv[qglob * 16 + round] = g;
                    topi[qglob * 16 + round] = ci[j];
                    cv[j] = NEG_INF; done = true;
                }
            }
        }
    }
}

// ---------------- softmax gather + subjective-logic fusion (K=2) ----------------
__global__ __launch_bounds__(256) void k_fuse(const float* __restrict__ topv,
                                              const int* __restrict__ topi,
                                              const float* __restrict__ mem_ev,
                                              const float* __restrict__ model_ev,
                                              float* __restrict__ out) {
    int q = blockIdx.x * blockDim.x + threadIdx.x;
    if (q >= B_Q) return;
    float tv[16]; int ti[16];
#pragma unroll
    for (int j = 0; j < 16; ++j) { tv[j] = topv[q * 16 + j]; ti[j] = topi[q * 16 + j]; }
    float mx = tv[0];
#pragma unroll
    for (int j = 1; j < 16; ++j) mx = fmaxf(mx, tv[j]);
    float es[16], ssum = 0.f;
#pragma unroll
    for (int j = 0; j < 16; ++j) { es[j] = expf((tv[j] - mx) * INV_T); ssum += es[j]; }
    float inv_s = 1.0f / ssum;
    float ar0 = 0.f, ar1 = 0.f;
#pragma unroll
    for (int j = 0; j < 16; ++j) {
        float w = es[j] * inv_s;
        const float* e = mem_ev + (size_t)ti[j] * 2;
        ar0 = fmaf(w, e[0], ar0);
        ar1 = fmaf(w, e[1], ar1);
    }
    float am0 = model_ev[q * 2 + 0] + 1.0f;
    float am1 = model_ev[q * 2 + 1] + 1.0f;
    float arr0 = ar0 + 1.0f, arr1 = ar1 + 1.0f;

    auto belief = [](float a0, float a1, float& b0, float& b1, float& u) {
        float S = fmaxf(a0 + a1, EPSF);
        b0 = fmaxf((a0 - 1.f) / S, 0.f);
        b1 = fmaxf((a1 - 1.f) / S, 0.f);
        u  = fminf(fmaxf(2.f / S, EPSF), 1.f - EPSF);
        float bs = b0 + b1;
        float target = fmaxf(1.f - u, EPSF);
        float sc = target / fmaxf(bs, EPSF);
        b0 *= sc; b1 *= sc;
    };
    float bm0, bm1, um, br0, br1, ur;
    belief(am0, am1, bm0, bm1, um);
    belief(arr0, arr1, br0, br1, ur);

    float total_pair = (bm0 + bm1) * (br0 + br1);
    float dot_same   = bm0 * br0 + bm1 * br1;
    float C = total_pair - dot_same;
    float S = fmaxf(1.f - C, EPSF);
    float b0 = (bm0 * br0 + bm0 * ur + br0 * um) / S;
    float b1 = (bm1 * br1 + bm1 * ur + br1 * um) / S;
    float u  = um * ur / S;
    b0 = fmaxf(b0, 0.f); b1 = fmaxf(b1, 0.f);
    u = fminf(fmaxf(u, EPSF), 1.f - EPSF);
    float bs = b0 + b1;
    float sc = (1.f - u) / fmaxf(bs, EPSF);
    b0 *= sc; b1 *= sc;
    float Sf = 2.f / u;
    float a0 = b0 * Sf + 1.f, a1 = b1 * Sf + 1.f;
    out[q * 2 + 0] = fmaxf(a0, 1.f + EPSF);
    out[q * 2 + 1] = fmaxf(a1, 1.f + EPSF);
}

// ---------------- launch ----------------
extern "C" void kernel_launch(void* const* d_in, const int* in_sizes, int n_in,
                              void* d_out, int out_size, void* d_ws, size_t ws_size,
                              hipStream_t stream) {
    const float* query    = (const float*)d_in[0];
    const float* mem      = (const float*)d_in[1];
    const float* mem_ev   = (const float*)d_in[2];
    const float* model_ev = (const float*)d_in[3];
    char* ws = (char*)d_ws;
    // ws layout (bytes): invq 4K | invm 400K | part_v 512K | part_i 512K | topv 64K | topi 64K | sims 51.2M
    float* invq   = (float*)(ws + 0);
    float* invm   = (float*)(ws + 4096);
    float* part_v = (float*)(ws + 404480);
    int*   part_i = (int*)  (ws + 404480 + 524288);
    float* topv   = (float*)(ws + 1453056);
    int*   topi   = (int*)  (ws + 1518592);
    float* sims   = (float*)(ws + 1585152);           // 128 * 100000 * 4B = 51.2 MB

    k_norms<<<(N_MEM + B_Q + 3) / 4, 256, 0, stream>>>(query, mem, invq, invm);
    for (int c = 0; c < NCHUNK; ++c) {
        k_gemm<<<(N_MEM + BR - 1) / BR, 256, 0, stream>>>(query, mem, invq, invm, sims, c);
        k_topk_part<<<dim3(CQ, SPLITS), 64, 0, stream>>>(sims, part_v, part_i);
        k_topk_merge<<<32, 256, 0, stream>>>(part_v, part_i, topv, topi, c);
    }
    k_fuse<<<4, 256, 0, stream>>>(topv, topi, mem_ev, model_ev, (float*)d_out);
}

// Round 14
// 1137.605 us; speedup vs baseline: 2.2476x; 1.5788x over previous
//
#include <hip/hip_runtime.h>
#include <cstdint>
#include <cstddef>

#define B_Q 1024
#define N_MEM 100000
#define DIM 256
#define CQ 128                 // queries per chunk
#define NCHUNK (B_Q / CQ)      // 8
#define BRG 128                // memory rows per gemm block tile
#define RSTRIDE 100000         // sims row stride (floats) per query
#define SPLITS 32
#define SPLIT_ROWS 3125        // N_MEM / SPLITS
#define EPSF 1e-8f
#define INV_T (1.0f / 0.07f)
#define NEG_INF (-1e30f)

typedef short bf16x8 __attribute__((ext_vector_type(8)));
typedef float f32x16 __attribute__((ext_vector_type(16)));

#define MIN16(t) fminf(fminf(fminf(fminf(t[0],t[1]),fminf(t[2],t[3])),fminf(fminf(t[4],t[5]),fminf(t[6],t[7]))), \
                       fminf(fminf(fminf(t[8],t[9]),fminf(t[10],t[11])),fminf(fminf(t[12],t[13]),fminf(t[14],t[15]))))
#define MAX16(t) fmaxf(fmaxf(fmaxf(fmaxf(t[0],t[1]),fmaxf(t[2],t[3])),fmaxf(fmaxf(t[4],t[5]),fmaxf(t[6],t[7]))), \
                       fmaxf(fmaxf(fmaxf(t[8],t[9]),fmaxf(t[10],t[11])),fmaxf(fmaxf(t[12],t[13]),fmaxf(t[14],t[15]))))
#define MAX8(t) fmaxf(fmaxf(fmaxf(t[0],t[1]),fmaxf(t[2],t[3])),fmaxf(fmaxf(t[4],t[5]),fmaxf(t[6],t[7])))

__device__ __forceinline__ unsigned short f2bf(float f) {   // RTN-even fp32->bf16
    unsigned int b = __float_as_uint(f);
    b += 0x7fffu + ((b >> 16) & 1u);
    return (unsigned short)(b >> 16);
}

// ---------------- norms: inv L2 norm of every memory row and query row ----------------
__global__ __launch_bounds__(256) void k_norms(const float* __restrict__ q,
                                               const float* __restrict__ m,
                                               float* __restrict__ invq,
                                               float* __restrict__ invm) {
    int wid  = blockIdx.x * 4 + (threadIdx.x >> 6);
    int lane = threadIdx.x & 63;
    if (wid >= N_MEM + B_Q) return;
    const float* src = (wid < N_MEM) ? (m + (size_t)wid * DIM)
                                     : (q + (size_t)(wid - N_MEM) * DIM);
    float4 v = ((const float4*)src)[lane];
    float ss = v.x*v.x + v.y*v.y + v.z*v.z + v.w*v.w;
#pragma unroll
    for (int off = 32; off > 0; off >>= 1) ss += __shfl_xor(ss, off);
    if (lane == 0) {
        float inv = 1.0f / fmaxf(sqrtf(ss), EPSF);
        if (wid < N_MEM) invm[wid] = inv;
        else             invq[wid - N_MEM] = inv;
    }
}

// ---------------- bf16 MFMA ranking GEMM: sims[q][r] ~ dot(q, m*invm) ----------------
// Block 256 thr = 4 waves; tile 128q x 128r; wave w: rows [32w,32w+32) x 128 r.
// On-the-fly fp32->bf16 (hi only) with invm folded into B. K staged 32 at a time.
// LDS layout [ksub(4)][row(128)][8 bf16] -> fragment reads are lane-contiguous (conflict-free).
// A and B packed with the SAME (lane-group,reg)->k convention => any HW k-permutation cancels.
__global__ __launch_bounds__(256) void k_gemm_mfma(const float* __restrict__ query,
                                                   const float* __restrict__ mem,
                                                   const float* __restrict__ invm,
                                                   float* __restrict__ sims,
                                                   int chunk) {
    __shared__ bf16x8 qs[4 * 128];   // 8 KB
    __shared__ bf16x8 ms[4 * 128];   // 8 KB
    const int tid  = threadIdx.x;
    const int w    = tid >> 6;        // wave 0..3 -> q rows [32w, 32w+32)
    const int ln   = tid & 63;
    const int ln31 = ln & 31;
    const int half = ln >> 5;         // k-halves within K=16 step
    const int rowbase = blockIdx.x * BRG;
    const int wq32 = w * 32;

    f32x16 acc[4];
#pragma unroll
    for (int rs = 0; rs < 4; ++rs)
#pragma unroll
        for (int t = 0; t < 16; ++t) acc[rs][t] = 0.f;

    const float* qbase = query + (size_t)(chunk * CQ) * DIM;

    for (int s = 0; s < 8; ++s) {                 // 8 K-stages of 32
        const int k0 = s * 32;
        __syncthreads();
#pragma unroll
        for (int p = 0; p < 2; ++p) {
            int j   = p * 256 + tid;              // 512 jobs: 128 rows x 4 k-segments
            int row = j >> 2, seg = j & 3;
            // queries (unnormalized; invq is ranking-invariant per q)
            const float* qp = qbase + (size_t)row * DIM + k0 + seg * 8;
            float4 a0 = *(const float4*)qp, a1 = *(const float4*)(qp + 4);
            bf16x8 qv;
            qv[0]=f2bf(a0.x); qv[1]=f2bf(a0.y); qv[2]=f2bf(a0.z); qv[3]=f2bf(a0.w);
            qv[4]=f2bf(a1.x); qv[5]=f2bf(a1.y); qv[6]=f2bf(a1.z); qv[7]=f2bf(a1.w);
            qs[seg * 128 + row] = qv;
            // memory rows, scaled by invm (zero-pad OOB rows -> never beat real top-16)
            int grow = rowbase + row;
            bf16x8 mv;
            if (grow < N_MEM) {
                float sc = invm[grow];
                const float* mp = mem + (size_t)grow * DIM + k0 + seg * 8;
                float4 b0 = *(const float4*)mp, b1 = *(const float4*)(mp + 4);
                mv[0]=f2bf(b0.x*sc); mv[1]=f2bf(b0.y*sc); mv[2]=f2bf(b0.z*sc); mv[3]=f2bf(b0.w*sc);
                mv[4]=f2bf(b1.x*sc); mv[5]=f2bf(b1.y*sc); mv[6]=f2bf(b1.z*sc); mv[7]=f2bf(b1.w*sc);
            } else {
#pragma unroll
                for (int e = 0; e < 8; ++e) mv[e] = 0;
            }
            ms[seg * 128 + row] = mv;
        }
        __syncthreads();
#pragma unroll
        for (int kst = 0; kst < 2; ++kst) {       // two K=16 MFMA steps
            bf16x8 af = qs[(kst * 2 + half) * 128 + wq32 + ln31];
#pragma unroll
            for (int rs = 0; rs < 4; ++rs) {
                bf16x8 bf = ms[(kst * 2 + half) * 128 + rs * 32 + ln31];
                acc[rs] = __builtin_amdgcn_mfma_f32_32x32x16_bf16(af, bf, acc[rs], 0, 0, 0);
            }
        }
    }
    // C/D layout (verified): col = lane&31, row = (reg&3) + 8*(reg>>2) + 4*(lane>>5)
#pragma unroll
    for (int rs = 0; rs < 4; ++rs) {
        int rcol = rowbase + rs * 32 + ln31;
        if (rcol < N_MEM) {
#pragma unroll
            for (int t = 0; t < 16; ++t) {
                int qrow = wq32 + (t & 3) + 8 * (t >> 2) + 4 * half;
                sims[(size_t)qrow * RSTRIDE + rcol] = acc[rs][t];
            }
        }
    }
}

// ---------------- per-(query, split) approx top-16: 4 waves/block, float4 scan ----------------
__global__ __launch_bounds__(256) void k_topk_part(const float* __restrict__ sims,
                                                   float* __restrict__ part_v,
                                                   int* __restrict__ part_i) {
    const int qc   = blockIdx.x;                  // 0..127
    const int s    = blockIdx.y * 4 + (threadIdx.x >> 6);  // 0..31
    const int lane = threadIdx.x & 63;
    const float* base = sims + (size_t)qc * RSTRIDE + s * SPLIT_ROWS;

    float tv[16]; int ti[16];
#pragma unroll
    for (int j = 0; j < 16; ++j) { tv[j] = NEG_INF; ti[j] = 0; }
    float cmin = NEG_INF;
    const int ibase = s * SPLIT_ROWS;

    for (int it = 0; it < 12; ++it) {             // 12*256 = 3072 rows
        int ro = it * 256 + lane * 4;
        float4 v4 = *(const float4*)(base + ro);
        float vv[4] = {v4.x, v4.y, v4.z, v4.w};
#pragma unroll
        for (int e = 0; e < 4; ++e) {
            float v = vv[e];
            if (v > cmin) {
                bool done = false;
#pragma unroll
                for (int j = 0; j < 16; ++j) {
                    bool hit = (!done) && (tv[j] == cmin);
                    if (hit) { tv[j] = v; ti[j] = ibase + ro + e; done = true; }
                }
                cmin = MIN16(tv);
            }
        }
    }
    if (lane < 53) {                              // tail 3072..3124
        int ro = 3072 + lane;
        float v = base[ro];
        if (v > cmin) {
            bool done = false;
#pragma unroll
            for (int j = 0; j < 16; ++j) {
                bool hit = (!done) && (tv[j] == cmin);
                if (hit) { tv[j] = v; ti[j] = ibase + ro; done = true; }
            }
        }
    }
    for (int round = 0; round < 16; ++round) {
        float mymax = MAX16(tv);
        float g = mymax;
#pragma unroll
        for (int off = 32; off > 0; off >>= 1) g = fmaxf(g, __shfl_xor(g, off));
        unsigned long long bal = __ballot(mymax == g);
        int winner = __ffsll(bal) - 1;
        if (lane == winner) {
            bool done = false;
#pragma unroll
            for (int j = 0; j < 16; ++j) {
                bool hit = (!done) && (tv[j] == g);
                if (hit) {
                    part_v[qc * (SPLITS * 16) + s * 16 + round] = g;
                    part_i[qc * (SPLITS * 16) + s * 16 + round] = ti[j];
                    tv[j] = NEG_INF; done = true;
                }
            }
        }
    }
}

// ---------------- merge 32x16 partials -> approx top-32 indices per query ----------------
__global__ __launch_bounds__(256) void k_topk_merge(const float* __restrict__ part_v,
                                                    const int* __restrict__ part_i,
                                                    int* __restrict__ topi32,
                                                    int chunk) {
    const int tid  = threadIdx.x;
    const int lane = tid & 63;
    const int qc   = blockIdx.x * 4 + (tid >> 6);
    float cv[8]; int ci[8];
#pragma unroll
    for (int t = 0; t < 8; ++t) {
        cv[t] = part_v[qc * 512 + t * 64 + lane];
        ci[t] = part_i[qc * 512 + t * 64 + lane];
    }
    const int qglob = chunk * CQ + qc;
    for (int round = 0; round < 32; ++round) {
        float mymax = MAX8(cv);
        float g = mymax;
#pragma unroll
        for (int off = 32; off > 0; off >>= 1) g = fmaxf(g, __shfl_xor(g, off));
        unsigned long long bal = __ballot(mymax == g);
        int winner = __ffsll(bal) - 1;
        if (lane == winner) {
            bool done = false;
#pragma unroll
            for (int j = 0; j < 8; ++j) {
                bool hit = (!done) && (cv[j] == g);
                if (hit) {
                    topi32[qglob * 32 + round] = ci[j];
                    cv[j] = NEG_INF; done = true;
                }
            }
        }
    }
}

// ---------------- exact fp32 rescore of 32 candidates -> true top-16 (sorted) ----------------
__global__ __launch_bounds__(256) void k_rescore(const float* __restrict__ query,
                                                 const float* __restrict__ mem,
                                                 const float* __restrict__ invq,
                                                 const float* __restrict__ invm,
                                                 const int* __restrict__ topi32,
                                                 float* __restrict__ topv,
                                                 int* __restrict__ topi) {
    __shared__ float cvs[32];
    __shared__ int   cis[32];
    const int qg   = blockIdx.x;                  // global query
    const int w    = threadIdx.x >> 6;
    const int lane = threadIdx.x & 63;
    const float4 qv = ((const float4*)(query + (size_t)qg * DIM))[lane];
    const float iq = invq[qg];
#pragma unroll
    for (int c = 0; c < 8; ++c) {
        int slot = w * 8 + c;
        int ridx = topi32[qg * 32 + slot];
        float4 mv = ((const float4*)(mem + (size_t)ridx * DIM))[lane];
        float d = qv.x*mv.x + qv.y*mv.y + qv.z*mv.z + qv.w*mv.w;
#pragma unroll
        for (int off = 32; off > 0; off >>= 1) d += __shfl_xor(d, off);
        if (lane == 0) {
            cvs[slot] = d * iq * invm[ridx];
            cis[slot] = ridx;
        }
    }
    __syncthreads();
    if (w == 0) {
        float v = (lane < 32) ? cvs[lane] : NEG_INF;
        int   i = (lane < 32) ? cis[lane] : 0;
        for (int round = 0; round < 16; ++round) {
            float g = v;
#pragma unroll
            for (int off = 32; off > 0; off >>= 1) g = fmaxf(g, __shfl_xor(g, off));
            unsigned long long bal = __ballot(v == g);
            int winner = __ffsll(bal) - 1;
            if (lane == winner) {
                topv[qg * 16 + round] = g;
                topi[qg * 16 + round] = i;
                v = NEG_INF;
            }
        }
    }
}

// ---------------- softmax gather + subjective-logic fusion (K=2) ----------------
__global__ __launch_bounds__(256) void k_fuse(const float* __restrict__ topv,
                                              const int* __restrict__ topi,
                                              const float* __restrict__ mem_ev,
                                              const float* __restrict__ model_ev,
                                              float* __restrict__ out) {
    int q = blockIdx.x * blockDim.x + threadIdx.x;
    if (q >= B_Q) return;
    float tv[16]; int ti[16];
#pragma unroll
    for (int j = 0; j < 16; ++j) { tv[j] = topv[q * 16 + j]; ti[j] = topi[q * 16 + j]; }
    float mx = tv[0];
#pragma unroll
    for (int j = 1; j < 16; ++j) mx = fmaxf(mx, tv[j]);
    float es[16], ssum = 0.f;
#pragma unroll
    for (int j = 0; j < 16; ++j) { es[j] = expf((tv[j] - mx) * INV_T); ssum += es[j]; }
    float inv_s = 1.0f / ssum;
    float ar0 = 0.f, ar1 = 0.f;
#pragma unroll
    for (int j = 0; j < 16; ++j) {
        float w = es[j] * inv_s;
        const float* e = mem_ev + (size_t)ti[j] * 2;
        ar0 = fmaf(w, e[0], ar0);
        ar1 = fmaf(w, e[1], ar1);
    }
    float am0 = model_ev[q * 2 + 0] + 1.0f;
    float am1 = model_ev[q * 2 + 1] + 1.0f;
    float arr0 = ar0 + 1.0f, arr1 = ar1 + 1.0f;

    auto belief = [](float a0, float a1, float& b0, float& b1, float& u) {
        float S = fmaxf(a0 + a1, EPSF);
        b0 = fmaxf((a0 - 1.f) / S, 0.f);
        b1 = fmaxf((a1 - 1.f) / S, 0.f);
        u  = fminf(fmaxf(2.f / S, EPSF), 1.f - EPSF);
        float bs = b0 + b1;
        float target = fmaxf(1.f - u, EPSF);
        float sc = target / fmaxf(bs, EPSF);
        b0 *= sc; b1 *= sc;
    };
    float bm0, bm1, um, br0, br1, ur;
    belief(am0, am1, bm0, bm1, um);
    belief(arr0, arr1, br0, br1, ur);

    float total_pair = (bm0 + bm1) * (br0 + br1);
    float dot_same   = bm0 * br0 + bm1 * br1;
    float C = total_pair - dot_same;
    float S = fmaxf(1.f - C, EPSF);
    float b0 = (bm0 * br0 + bm0 * ur + br0 * um) / S;
    float b1 = (bm1 * br1 + bm1 * ur + br1 * um) / S;
    float u  = um * ur / S;
    b0 = fmaxf(b0, 0.f); b1 = fmaxf(b1, 0.f);
    u = fminf(fmaxf(u, EPSF), 1.f - EPSF);
    float bs = b0 + b1;
    float sc = (1.f - u) / fmaxf(bs, EPSF);
    b0 *= sc; b1 *= sc;
    float Sf = 2.f / u;
    float a0 = b0 * Sf + 1.f, a1 = b1 * Sf + 1.f;
    out[q * 2 + 0] = fmaxf(a0, 1.f + EPSF);
    out[q * 2 + 1] = fmaxf(a1, 1.f + EPSF);
}

// ---------------- launch ----------------
extern "C" void kernel_launch(void* const* d_in, const int* in_sizes, int n_in,
                              void* d_out, int out_size, void* d_ws, size_t ws_size,
                              hipStream_t stream) {
    const float* query    = (const float*)d_in[0];
    const float* mem      = (const float*)d_in[1];
    const float* mem_ev   = (const float*)d_in[2];
    const float* model_ev = (const float*)d_in[3];
    char* ws = (char*)d_ws;
    float* invq   = (float*)(ws + 0);          //   4 KB
    float* invm   = (float*)(ws + 4096);       // 400 KB
    float* part_v = (float*)(ws + 413696);     // 256 KB
    int*   part_i = (int*)  (ws + 675840);     // 256 KB
    int*   topi32 = (int*)  (ws + 937984);     // 128 KB
    float* topv   = (float*)(ws + 1069056);    //  64 KB
    int*   topi   = (int*)  (ws + 1134592);    //  64 KB
    float* sims   = (float*)(ws + 1200128);    // 51.2 MB -> total ~52.4 MB

    k_norms<<<(N_MEM + B_Q + 3) / 4, 256, 0, stream>>>(query, mem, invq, invm);
    for (int c = 0; c < NCHUNK; ++c) {
        k_gemm_mfma<<<(N_MEM + BRG - 1) / BRG, 256, 0, stream>>>(query, mem, invm, sims, c);
        k_topk_part<<<dim3(CQ, 8), 256, 0, stream>>>(sims, part_v, part_i);
        k_topk_merge<<<32, 256, 0, stream>>>(part_v, part_i, topi32, c);
    }
    k_rescore<<<B_Q, 256, 0, stream>>>(query, mem, invq, invm, topi32, topv, topi);
    k_fuse<<<4, 256, 0, stream>>>(topv, topi, mem_ev, model_ev, (float*)d_out);
}